// Round 6
// baseline (105.078 us; speedup 1.0000x reference)
//
#include <hip/hip_runtime.h>
#include <math.h>

// Problem constants: [N, L, H, D] = [4, 8192, 8, 64], Dv = 64, fp32 in/out.
#define N_    4
#define L_    8192
#define H_    8
#define NH_   32           // N*H
#define CHK   64           // chunk length
#define NSEG  32           // segments per (n,h)
#define SEGC  4            // chunks per segment
#define NC_   128          // chunks per (n,h)
#define ROWF  512          // H_*D_ floats between consecutive l
#define EPSF  1e-6f

typedef __attribute__((ext_vector_type(8))) short bf16x8;   // 8 bf16 = 4 VGPRs
typedef __attribute__((ext_vector_type(4))) float f32x4;
typedef __attribute__((ext_vector_type(4))) unsigned short us4;

__device__ __forceinline__ float fmap(float x) { return x > 0.f ? x + 1.f : __expf(x); }

__device__ __forceinline__ unsigned short f2bf(float x) {
  unsigned u = __float_as_uint(x);
  u += 0x7FFFu + ((u >> 16) & 1u);       // round-to-nearest-even
  return (unsigned short)(u >> 16);
}
__device__ __forceinline__ float bf2f(unsigned short u) {
  return __uint_as_float(((unsigned)u) << 16);
}

// Swizzled ushort index into a row-major [64] bf16 tile (row stride 128 B).
__device__ __forceinline__ int sidx(int row, int col) {
  return row * 64 + (col ^ ((row & 7) << 3));
}

__device__ __forceinline__ f32x4 MFMA(bf16x8 a, bf16x8 b, f32x4 c) {
  return __builtin_amdgcn_mfma_f32_16x16x32_bf16(a, b, c, 0, 0, 0);
}

// ---------------- Pass A: segment sums + per-chunk intra-segment exclusive prefixes ----------------
__global__ __launch_bounds__(256) void k_seg_sums(const float* __restrict__ keys,
                                                  const float* __restrict__ values,
                                                  float* __restrict__ SegTot,
                                                  unsigned short* __restrict__ IntraPre,
                                                  float* __restrict__ KsegTot,
                                                  float* __restrict__ KintraPre) {
  __shared__ unsigned short Kt[64 * 64];  // K^T [d][s] (fmap, bf16)
  __shared__ unsigned short Vt[64 * 64];  // V^T [e][s]
  __shared__ float kacc[64];
  const int bid = blockIdx.x;             // nh*NSEG + seg
  const int nh = bid / NSEG, seg = bid % NSEG;
  const int n = nh / H_, h = nh % H_;
  const int tid = threadIdx.x;
  const int lane = tid & 63;
  const int wv = tid >> 6;
  const int lane15 = lane & 15, lg = lane >> 4;
  const int arow = wv * 16 + lane15;      // Vt row (e) for B-operand fragments

  if (tid < 64) kacc[tid] = 0.f;
  __syncthreads();

  // sAcc[nt] holds S^T[e = wv*16+lane15][d = nt*16 + lg*4 + r]  (swapped-operand C layout)
  f32x4 sAcc[4];
#pragma unroll
  for (int nt = 0; nt < 4; ++nt) sAcc[nt] = (f32x4){0.f, 0.f, 0.f, 0.f};

  // staging thread map: d4 = tid>>4 (4-col group), sg = tid&15 (4-row group)
  const int d4 = tid >> 4, sg = tid & 15;

  for (int ci = 0; ci < SEGC; ++ci) {
    const int c = seg * SEGC + ci;
    const int l0 = c * CHK;
    float kp[4] = {0.f, 0.f, 0.f, 0.f};
    // row-major float4 loads, transpose-write to LDS (u16 scatter)
#pragma unroll
    for (int j = 0; j < 4; ++j) {
      const int s = sg * 4 + j;
      const size_t g = ((size_t)(n * L_ + l0 + s)) * ROWF + h * 64 + d4 * 4;
      const float4 k4 = *(const float4*)&keys[g];
      const float4 v4 = *(const float4*)&values[g];
      const float kf[4] = {fmap(k4.x), fmap(k4.y), fmap(k4.z), fmap(k4.w)};
      const float vf[4] = {v4.x, v4.y, v4.z, v4.w};
#pragma unroll
      for (int m = 0; m < 4; ++m) {
        kp[m] += kf[m];
        Kt[sidx(d4 * 4 + m, s)] = f2bf(kf[m]);
        Vt[sidx(d4 * 4 + m, s)] = f2bf(vf[m]);
      }
    }
    // exclusive intra-segment prefix snapshot (pre-update state): us4 stores
    {
      unsigned short* ip = IntraPre + ((size_t)nh * NC_ + c) * 4096;
      const int e = wv * 16 + lane15;
#pragma unroll
      for (int nt = 0; nt < 4; ++nt) {
        us4 w;
#pragma unroll
        for (int r = 0; r < 4; ++r) w[r] = f2bf(sAcc[nt][r]);
        *(us4*)&ip[(size_t)e * 64 + nt * 16 + lg * 4] = w;
      }
    }
    if (tid < 64) KintraPre[((size_t)nh * NC_ + c) * 64 + tid] = kacc[tid];
    __syncthreads();  // B1: staging + kacc snapshot done

    // reduce kp over the 16-lane group (lanes sharing d4), then one atomic per col
#pragma unroll
    for (int m = 0; m < 4; ++m) {
      float v = kp[m];
      v += __shfl_xor(v, 1);
      v += __shfl_xor(v, 2);
      v += __shfl_xor(v, 4);
      v += __shfl_xor(v, 8);
      if (lane15 == 0) atomicAdd(&kacc[d4 * 4 + m], v);
    }

    const bf16x8 av0 = *(const bf16x8*)&Vt[sidx(arow, lg * 8)];
    const bf16x8 av1 = *(const bf16x8*)&Vt[sidx(arow, (lg + 4) * 8)];
#pragma unroll
    for (int nt = 0; nt < 4; ++nt) {
      const int brow = nt * 16 + lane15;   // Kt row (d) window
      sAcc[nt] = MFMA(*(const bf16x8*)&Kt[sidx(brow, lg * 8)], av0, sAcc[nt]);
      sAcc[nt] = MFMA(*(const bf16x8*)&Kt[sidx(brow, (lg + 4) * 8)], av1, sAcc[nt]);
    }
    __syncthreads();  // B2: Kt/Vt reads + atomics drained before restage
  }

  // write segment totals: lane holds S^T[e][4 consecutive d] -> float4 stores
  {
    float* Sg = SegTot + (size_t)bid * 4096;
    const int e = wv * 16 + lane15;
#pragma unroll
    for (int nt = 0; nt < 4; ++nt) {
      const float4 w = make_float4(sAcc[nt][0], sAcc[nt][1], sAcc[nt][2], sAcc[nt][3]);
      *(float4*)&Sg[(size_t)e * 64 + nt * 16 + lg * 4] = w;
    }
  }
  if (tid < 64) KsegTot[(size_t)bid * 64 + tid] = kacc[tid];
}

// ---------------- Pass B: exclusive prefix over segment totals (in place) ----------------
__global__ __launch_bounds__(256) void k_prefix(float* __restrict__ SegTot, float* __restrict__ KsegTot) {
  const int tid = threadIdx.x;
  if (blockIdx.x < 512) {
    const int gid = blockIdx.x * 256 + tid;          // 0 .. 131071
    const int nh = gid >> 12, de = gid & 4095;
    float* p = SegTot + (size_t)nh * NSEG * 4096 + de;
    float run = 0.f;
    for (int s = 0; s < NSEG; ++s) {
      const float x = p[(size_t)s * 4096];
      p[(size_t)s * 4096] = run;
      run += x;
    }
  } else {
    const int gid = (blockIdx.x - 512) * 256 + tid;  // 0 .. 2047
    const int nh = gid >> 6, d = gid & 63;
    float* p = KsegTot + (size_t)nh * NSEG * 64 + d;
    float run = 0.f;
    for (int s = 0; s < NSEG; ++s) {
      const float x = p[s * 64];
      p[s * 64] = run;
      run += x;
    }
  }
}

// ---------------- Pass C: per-chunk output (4096 blocks) ----------------
__global__ __launch_bounds__(256, 6) void k_output(const float* __restrict__ queries,
                                                   const float* __restrict__ keys,
                                                   const float* __restrict__ values,
                                                   const float* __restrict__ SegPre,
                                                   const unsigned short* __restrict__ IntraPre,
                                                   const float* __restrict__ KsegPre,
                                                   const float* __restrict__ KintraPre,
                                                   float* __restrict__ out) {
  __shared__ unsigned short Ks[64 * 64];  // K row-major (fmap); after B2: attn rows (wave-local)
  __shared__ unsigned short Vt[64 * 64];  // V^T [e][s]
  __shared__ unsigned short St[64 * 64];  // S^T prefix [e][d] bf16
  __shared__ float kpre[64];

  // XCD-aware swizzle: 4096 % 8 == 0 -> bijective; neighboring chunks share an XCD's L2
  const int wg = blockIdx.x;
  const int bid = (wg & 7) * (NH_ * NC_ / 8) + (wg >> 3);
  const int nh = bid / NC_, c = bid % NC_;
  const int seg = c / SEGC;
  const int n = nh / H_, h = nh % H_;
  const int tid = threadIdx.x;
  const int lane = tid & 63;
  const int wv = tid >> 6;
  const int lane15 = lane & 15, lg = lane >> 4;
  const int t0w = wv * 16;
  const int trow = t0w + lane15;          // this lane's attn/output row (wave-local)
  const int l0 = c * CHK;

  // ---- staging ----
  // K row-major (fmap, bf16): float4 loads
  {
    const int r0 = tid >> 4, c4 = (tid & 15) * 4;
    for (int rep = 0; rep < 4; ++rep) {
      const int row = r0 + rep * 16;
      const size_t g = ((size_t)(n * L_ + l0 + row)) * ROWF + h * 64 + c4;
      const float4 k = *(const float4*)&keys[g];
      us4 uk;
      uk[0] = f2bf(fmap(k.x)); uk[1] = f2bf(fmap(k.y));
      uk[2] = f2bf(fmap(k.z)); uk[3] = f2bf(fmap(k.w));
      *(us4*)&Ks[sidx(row, c4)] = uk;
    }
  }
  // V^T: row-major float4 loads + u16 transpose-scatter
  {
    const int d4 = tid >> 4, sg = tid & 15;
#pragma unroll
    for (int j = 0; j < 4; ++j) {
      const int s = sg * 4 + j;
      const float4 v4 = *(const float4*)&values[((size_t)(n * L_ + l0 + s)) * ROWF + h * 64 + d4 * 4];
      const float vf[4] = {v4.x, v4.y, v4.z, v4.w};
#pragma unroll
      for (int m = 0; m < 4; ++m) Vt[sidx(d4 * 4 + m, s)] = f2bf(vf[m]);
    }
  }
  // S^T prefix = SegPre (fp32) + IntraPre (bf16)
  {
    const float* sp = SegPre + ((size_t)nh * NSEG + seg) * 4096;
    const unsigned short* ip = IntraPre + ((size_t)nh * NC_ + c) * 4096;
    const int r0 = tid >> 4, c4 = (tid & 15) * 4;
    for (int rep = 0; rep < 4; ++rep) {
      const int row = r0 + rep * 16;
      const float4 s4 = *(const float4*)&sp[row * 64 + c4];
      const us4 i4 = *(const us4*)&ip[row * 64 + c4];
      us4 w;
      w[0] = f2bf(s4.x + bf2f(i4[0]));
      w[1] = f2bf(s4.y + bf2f(i4[1]));
      w[2] = f2bf(s4.z + bf2f(i4[2]));
      w[3] = f2bf(s4.w + bf2f(i4[3]));
      *(us4*)&St[sidx(row, c4)] = w;
    }
  }
  if (tid < 64)
    kpre[tid] = KsegPre[((size_t)nh * NSEG + seg) * 64 + tid] +
                KintraPre[((size_t)nh * NC_ + c) * 64 + tid];
  // Q fragments straight into registers (row trow, k-slices lg*8 / 32+lg*8)
  bf16x8 qf0, qf1;
  {
    const size_t qg = ((size_t)(n * L_ + l0 + trow)) * ROWF + h * 64;
    const float4 a = *(const float4*)&queries[qg + lg * 8];
    const float4 b = *(const float4*)&queries[qg + lg * 8 + 4];
    const float4 cc = *(const float4*)&queries[qg + 32 + lg * 8];
    const float4 d4 = *(const float4*)&queries[qg + 32 + lg * 8 + 4];
    qf0[0] = (short)f2bf(fmap(a.x)); qf0[1] = (short)f2bf(fmap(a.y));
    qf0[2] = (short)f2bf(fmap(a.z)); qf0[3] = (short)f2bf(fmap(a.w));
    qf0[4] = (short)f2bf(fmap(b.x)); qf0[5] = (short)f2bf(fmap(b.y));
    qf0[6] = (short)f2bf(fmap(b.z)); qf0[7] = (short)f2bf(fmap(b.w));
    qf1[0] = (short)f2bf(fmap(cc.x)); qf1[1] = (short)f2bf(fmap(cc.y));
    qf1[2] = (short)f2bf(fmap(cc.z)); qf1[3] = (short)f2bf(fmap(cc.w));
    qf1[4] = (short)f2bf(fmap(d4.x)); qf1[5] = (short)f2bf(fmap(d4.y));
    qf1[6] = (short)f2bf(fmap(d4.z)); qf1[7] = (short)f2bf(fmap(d4.w));
  }
  __syncthreads();  // B1: all tiles + kpre visible

  // ---- QK^T, swapped: lane holds attn[t = trow][s = nt*16 + lg*4 + r] ----
  f32x4 aT[4];
#pragma unroll
  for (int nt = 0; nt < 4; ++nt) {
    const int srow = nt * 16 + lane15;
    f32x4 a = {0.f, 0.f, 0.f, 0.f};
    a = MFMA(*(const bf16x8*)&Ks[sidx(srow, lg * 8)], qf0, a);
    a = MFMA(*(const bf16x8*)&Ks[sidx(srow, (lg + 4) * 8)], qf1, a);
    aT[nt] = a;
  }
  // zden inter-chunk term: in-register dot Q[trow] . kpre (partial over this lane's d-slice)
  float zp = 0.f;
#pragma unroll
  for (int j = 0; j < 8; ++j) zp += bf2f((unsigned short)qf0[j]) * kpre[lg * 8 + j];
#pragma unroll
  for (int j = 0; j < 8; ++j) zp += bf2f((unsigned short)qf1[j]) * kpre[32 + lg * 8 + j];

  __syncthreads();  // B2: all waves' Ks reads done (Ks becomes the attn buffer)

  // ---- mask + rowsum + attn rows into Ks (wave-local rows) ----
  float rs = 0.f;
#pragma unroll
  for (int nt = 0; nt < 4; ++nt) {
    us4 w;
#pragma unroll
    for (int r = 0; r < 4; ++r) {
      const int s = nt * 16 + lg * 4 + r;
      const float v = (s <= trow) ? aT[nt][r] : 0.f;
      rs += v;
      w[r] = f2bf(v);
    }
    *(us4*)&Ks[sidx(trow, nt * 16 + lg * 4)] = w;
  }
  // denominator for row trow: reduce the 4 lg-partials; zv stays lane-local
  float den = rs + zp;
  den += __shfl_xor(den, 16);
  den += __shfl_xor(den, 32);
  const float zv = 1.f / (den + EPSF);

  // ---- out^T-frags: lane holds out[trow][e = nt*16 + lg*4 + r] -> float4 stores ----
  const bf16x8 af0 = *(const bf16x8*)&Ks[sidx(trow, lg * 8)];
  const bf16x8 af1 = *(const bf16x8*)&Ks[sidx(trow, 32 + lg * 8)];
  const size_t obase = ((size_t)(n * L_ + l0 + trow)) * ROWF + h * 64;
#pragma unroll
  for (int nt = 0; nt < 4; ++nt) {
    const int brow = nt * 16 + lane15;   // Vt/St row (e) window
    f32x4 o = {0.f, 0.f, 0.f, 0.f};
    o = MFMA(*(const bf16x8*)&Vt[sidx(brow, lg * 8)], af0, o);
    o = MFMA(*(const bf16x8*)&Vt[sidx(brow, (lg + 4) * 8)], af1, o);
    o = MFMA(*(const bf16x8*)&St[sidx(brow, lg * 8)], qf0, o);
    o = MFMA(*(const bf16x8*)&St[sidx(brow, (lg + 4) * 8)], qf1, o);
    const float4 w = make_float4(o[0] * zv, o[1] * zv, o[2] * zv, o[3] * zv);
    *(float4*)&out[obase + nt * 16 + lg * 4] = w;
  }
}

extern "C" void kernel_launch(void* const* d_in, const int* in_sizes, int n_in,
                              void* d_out, int out_size, void* d_ws, size_t ws_size,
                              hipStream_t stream) {
  const float* queries = (const float*)d_in[0];
  const float* keys    = (const float*)d_in[1];
  const float* values  = (const float*)d_in[2];
  float* out = (float*)d_out;

  // workspace layout:
  //  SegTot   [NH_*NSEG][4096] fp32   (totals -> exclusive prefix in pass B)
  //  IntraPre [NH_*NC_ ][4096] bf16   (per-chunk intra-segment exclusive prefix)
  //  KsegTot  [NH_*NSEG][64]   fp32
  //  KintraPre[NH_*NC_ ][64]   fp32
  const size_t segtot_e = (size_t)NH_ * NSEG * 4096;
  const size_t intra_e  = (size_t)NH_ * NC_ * 4096;
  const size_t kseg_e   = (size_t)NH_ * NSEG * 64;
  const size_t kintra_e = (size_t)NH_ * NC_ * 64;
  const size_t need = segtot_e * 4 + intra_e * 2 + kseg_e * 4 + kintra_e * 4;
  if (ws_size < need) return;
  float* SegTot = (float*)d_ws;
  unsigned short* IntraPre = (unsigned short*)(SegTot + segtot_e);
  float* KsegTot = (float*)(IntraPre + intra_e);
  float* KintraPre = KsegTot + kseg_e;

  hipLaunchKernelGGL(k_seg_sums, dim3(NH_ * NSEG), dim3(256), 0, stream,
                     keys, values, SegTot, IntraPre, KsegTot, KintraPre);
  hipLaunchKernelGGL(k_prefix, dim3(512 + 8), dim3(256), 0, stream, SegTot, KsegTot);
  hipLaunchKernelGGL(k_output, dim3(NH_ * NC_), dim3(256), 0, stream,
                     queries, keys, values, SegTot, IntraPre, KsegTot, KintraPre, out);
}

// Round 7
// 96.213 us; speedup vs baseline: 1.0921x; 1.0921x over previous
//
#include <hip/hip_runtime.h>
#include <math.h>

// Problem constants: [N, L, H, D] = [4, 8192, 8, 64], Dv = 64, fp32 in/out.
#define N_    4
#define L_    8192
#define H_    8
#define NH_   32           // N*H
#define CHK   64           // chunk length
#define NC_   128          // chunks per (n,h)
#define ROWF  512          // H_*D_ floats between consecutive l
#define EPSF  1e-6f

typedef __attribute__((ext_vector_type(8))) short bf16x8;   // 8 bf16 = 4 VGPRs
typedef __attribute__((ext_vector_type(4))) float f32x4;
typedef __attribute__((ext_vector_type(4))) unsigned short us4;

__device__ __forceinline__ float fmap(float x) { return x > 0.f ? x + 1.f : __expf(x); }

__device__ __forceinline__ unsigned short f2bf(float x) {
  unsigned u = __float_as_uint(x);
  u += 0x7FFFu + ((u >> 16) & 1u);       // round-to-nearest-even
  return (unsigned short)(u >> 16);
}
__device__ __forceinline__ float bf2f(unsigned short u) {
  return __uint_as_float(((unsigned)u) << 16);
}

// Swizzled ushort index into a row-major [64] bf16 tile (row stride 128 B).
__device__ __forceinline__ int sidx(int row, int col) {
  return row * 64 + (col ^ ((row & 7) << 3));
}

__device__ __forceinline__ f32x4 MFMA(bf16x8 a, bf16x8 b, f32x4 c) {
  return __builtin_amdgcn_mfma_f32_16x16x32_bf16(a, b, c, 0, 0, 0);
}

// ---------------- Pass A: per-chunk totals T_c = (K^T V)^T and K column-sums ----------------
// 4096 blocks, no serial loop: max residency, short critical path.
__global__ __launch_bounds__(256) void k_chunk_tot(const float* __restrict__ keys,
                                                   const float* __restrict__ values,
                                                   unsigned short* __restrict__ Tws,
                                                   float* __restrict__ Kcs) {
  __shared__ unsigned short Kt[64 * 64];  // K^T [d][s] (fmap, bf16)
  __shared__ unsigned short Vt[64 * 64];  // V^T [e][s]
  __shared__ float kacc[64];
  const int bid = blockIdx.x;             // nh*NC_ + c
  const int nh = bid / NC_, c = bid % NC_;
  const int n = nh / H_, h = nh % H_;
  const int tid = threadIdx.x;
  const int lane = tid & 63;
  const int wv = tid >> 6;
  const int lane15 = lane & 15, lg = lane >> 4;
  const int arow = wv * 16 + lane15;      // e-row for the V fragment

  if (tid < 64) kacc[tid] = 0.f;

  // transposed staging (coalesced: lanes 0..63 read consecutive floats per s)
  float kpart = 0.f;
  {
    const int d = tid & 63, sg = tid >> 6;
    const size_t gbase = ((size_t)(n * L_ + c * CHK)) * ROWF + h * 64 + d;
    for (int rep = 0; rep < 4; ++rep) {
      const int s0 = (sg * 4 + rep) * 4;
      us4 wk, wvv;
#pragma unroll
      for (int j = 0; j < 4; ++j) {
        const size_t g = gbase + (size_t)(s0 + j) * ROWF;
        const float kf = fmap(keys[g]);
        kpart += kf;
        wk[j] = f2bf(kf);
        wvv[j] = f2bf(values[g]);
      }
      *(us4*)&Kt[sidx(d, s0)] = wk;
      *(us4*)&Vt[sidx(d, s0)] = wvv;
    }
  }
  __syncthreads();  // B1: tiles + kacc zero-init visible

  atomicAdd(&kacc[tid & 63], kpart);  // 4 adders per column

  // swapped MFMA: lane holds T[e = arow][d = nt*16 + lg*4 + r]
  const bf16x8 av0 = *(const bf16x8*)&Vt[sidx(arow, lg * 8)];
  const bf16x8 av1 = *(const bf16x8*)&Vt[sidx(arow, (lg + 4) * 8)];
  unsigned short* Tp = Tws + (size_t)bid * 4096;
#pragma unroll
  for (int nt = 0; nt < 4; ++nt) {
    const int brow = nt * 16 + lane15;   // d-window
    f32x4 acc = {0.f, 0.f, 0.f, 0.f};
    acc = MFMA(*(const bf16x8*)&Kt[sidx(brow, lg * 8)], av0, acc);
    acc = MFMA(*(const bf16x8*)&Kt[sidx(brow, (lg + 4) * 8)], av1, acc);
    us4 w;
#pragma unroll
    for (int r = 0; r < 4; ++r) w[r] = f2bf(acc[r]);
    *(us4*)&Tp[(size_t)arow * 64 + nt * 16 + lg * 4] = w;
  }
  __syncthreads();  // atomics done
  if (tid < 64) Kcs[(size_t)bid * 64 + tid] = kacc[tid];
}

// ---------------- Pass B: in-place exclusive prefix over chunks (depth 32, 4-wide) ----------------
__global__ __launch_bounds__(256) void k_scan(unsigned short* __restrict__ Tws,
                                              float* __restrict__ Kcs) {
  const int tid = threadIdx.x;
  if (blockIdx.x < 512) {
    const int gid = blockIdx.x * 256 + tid;          // 0 .. 131071
    const int nh = gid >> 12, de = gid & 4095;
    unsigned short* p = Tws + (size_t)nh * NC_ * 4096 + de;
    float run = 0.f;
    for (int s = 0; s < 32; ++s) {
      // 4 independent loads per step (issue together; depth = 32 not 128)
      const float x0 = bf2f(p[(size_t)(s * 4 + 0) * 4096]);
      const float x1 = bf2f(p[(size_t)(s * 4 + 1) * 4096]);
      const float x2 = bf2f(p[(size_t)(s * 4 + 2) * 4096]);
      const float x3 = bf2f(p[(size_t)(s * 4 + 3) * 4096]);
      p[(size_t)(s * 4 + 0) * 4096] = f2bf(run);
      p[(size_t)(s * 4 + 1) * 4096] = f2bf(run + x0);
      p[(size_t)(s * 4 + 2) * 4096] = f2bf(run + x0 + x1);
      p[(size_t)(s * 4 + 3) * 4096] = f2bf(run + x0 + x1 + x2);
      run += x0 + x1 + x2 + x3;
    }
  } else {
    const int gid = (blockIdx.x - 512) * 256 + tid;  // 0 .. 2047
    const int nh = gid >> 6, d = gid & 63;
    float* p = Kcs + (size_t)nh * NC_ * 64 + d;
    float run = 0.f;
    for (int s = 0; s < 32; ++s) {
      const float x0 = p[(size_t)(s * 4 + 0) * 64];
      const float x1 = p[(size_t)(s * 4 + 1) * 64];
      const float x2 = p[(size_t)(s * 4 + 2) * 64];
      const float x3 = p[(size_t)(s * 4 + 3) * 64];
      p[(size_t)(s * 4 + 0) * 64] = run;
      p[(size_t)(s * 4 + 1) * 64] = run + x0;
      p[(size_t)(s * 4 + 2) * 64] = run + x0 + x1;
      p[(size_t)(s * 4 + 3) * 64] = run + x0 + x1 + x2;
      run += x0 + x1 + x2 + x3;
    }
  }
}

// ---------------- Pass C: per-chunk output (4096 blocks) ----------------
__global__ __launch_bounds__(256, 6) void k_output(const float* __restrict__ queries,
                                                   const float* __restrict__ keys,
                                                   const float* __restrict__ values,
                                                   const unsigned short* __restrict__ Pws,
                                                   const float* __restrict__ Kpre,
                                                   float* __restrict__ out) {
  __shared__ unsigned short Ks[64 * 64];  // K row-major (fmap); after B2: attn rows (wave-local)
  __shared__ unsigned short Vt[64 * 64];  // V^T [e][s]
  __shared__ unsigned short St[64 * 64];  // S^T prefix [e][d] bf16
  __shared__ float kpre[64];

  // XCD-aware swizzle: 4096 % 8 == 0 -> bijective; neighboring chunks share an XCD's L2
  const int wg = blockIdx.x;
  const int bid = (wg & 7) * (NH_ * NC_ / 8) + (wg >> 3);
  const int nh = bid / NC_, c = bid % NC_;
  const int n = nh / H_, h = nh % H_;
  const int tid = threadIdx.x;
  const int lane = tid & 63;
  const int wv = tid >> 6;
  const int lane15 = lane & 15, lg = lane >> 4;
  const int t0w = wv * 16;
  const int trow = t0w + lane15;          // this lane's attn/output row (wave-local)
  const int l0 = c * CHK;

  // ---- staging ----
  // K row-major (fmap, bf16): float4 loads
  {
    const int r0 = tid >> 4, c4 = (tid & 15) * 4;
    for (int rep = 0; rep < 4; ++rep) {
      const int row = r0 + rep * 16;
      const size_t g = ((size_t)(n * L_ + l0 + row)) * ROWF + h * 64 + c4;
      const float4 k = *(const float4*)&keys[g];
      us4 uk;
      uk[0] = f2bf(fmap(k.x)); uk[1] = f2bf(fmap(k.y));
      uk[2] = f2bf(fmap(k.z)); uk[3] = f2bf(fmap(k.w));
      *(us4*)&Ks[sidx(row, c4)] = uk;
    }
  }
  // V^T: transposed coalesced loads + us4 writes
  {
    const int d = tid & 63, sg = tid >> 6;
    const size_t gbase = ((size_t)(n * L_ + l0)) * ROWF + h * 64 + d;
    for (int rep = 0; rep < 4; ++rep) {
      const int s0 = (sg * 4 + rep) * 4;
      us4 w;
#pragma unroll
      for (int j = 0; j < 4; ++j) w[j] = f2bf(values[gbase + (size_t)(s0 + j) * ROWF]);
      *(us4*)&Vt[sidx(d, s0)] = w;
    }
  }
  // S^T prefix: direct bf16 copy from ws
  {
    const unsigned short* pp = Pws + (size_t)bid * 4096;
    const int r0 = tid >> 4, c4 = (tid & 15) * 4;
    for (int rep = 0; rep < 4; ++rep) {
      const int row = r0 + rep * 16;
      *(us4*)&St[sidx(row, c4)] = *(const us4*)&pp[row * 64 + c4];
    }
  }
  if (tid < 64) kpre[tid] = Kpre[(size_t)bid * 64 + tid];
  // Q fragments straight into registers (row trow, k-slices lg*8 / 32+lg*8)
  bf16x8 qf0, qf1;
  {
    const size_t qg = ((size_t)(n * L_ + l0 + trow)) * ROWF + h * 64;
    const float4 a = *(const float4*)&queries[qg + lg * 8];
    const float4 b = *(const float4*)&queries[qg + lg * 8 + 4];
    const float4 cc = *(const float4*)&queries[qg + 32 + lg * 8];
    const float4 d4 = *(const float4*)&queries[qg + 32 + lg * 8 + 4];
    qf0[0] = (short)f2bf(fmap(a.x)); qf0[1] = (short)f2bf(fmap(a.y));
    qf0[2] = (short)f2bf(fmap(a.z)); qf0[3] = (short)f2bf(fmap(a.w));
    qf0[4] = (short)f2bf(fmap(b.x)); qf0[5] = (short)f2bf(fmap(b.y));
    qf0[6] = (short)f2bf(fmap(b.z)); qf0[7] = (short)f2bf(fmap(b.w));
    qf1[0] = (short)f2bf(fmap(cc.x)); qf1[1] = (short)f2bf(fmap(cc.y));
    qf1[2] = (short)f2bf(fmap(cc.z)); qf1[3] = (short)f2bf(fmap(cc.w));
    qf1[4] = (short)f2bf(fmap(d4.x)); qf1[5] = (short)f2bf(fmap(d4.y));
    qf1[6] = (short)f2bf(fmap(d4.z)); qf1[7] = (short)f2bf(fmap(d4.w));
  }
  __syncthreads();  // B1: all tiles + kpre visible

  // ---- QK^T, swapped: lane holds attn[t = trow][s = nt*16 + lg*4 + r] ----
  f32x4 aT[4];
#pragma unroll
  for (int nt = 0; nt < 4; ++nt) {
    const int srow = nt * 16 + lane15;
    f32x4 a = {0.f, 0.f, 0.f, 0.f};
    a = MFMA(*(const bf16x8*)&Ks[sidx(srow, lg * 8)], qf0, a);
    a = MFMA(*(const bf16x8*)&Ks[sidx(srow, (lg + 4) * 8)], qf1, a);
    aT[nt] = a;
  }
  // zden inter-chunk term: in-register dot Q[trow] . kpre (partial over this lane's d-slice)
  float zp = 0.f;
#pragma unroll
  for (int j = 0; j < 8; ++j) zp += bf2f((unsigned short)qf0[j]) * kpre[lg * 8 + j];
#pragma unroll
  for (int j = 0; j < 8; ++j) zp += bf2f((unsigned short)qf1[j]) * kpre[32 + lg * 8 + j];

  __syncthreads();  // B2: all waves' Ks reads done (Ks becomes the attn buffer)

  // ---- mask + rowsum + attn rows into Ks (wave-local rows) ----
  float rs = 0.f;
#pragma unroll
  for (int nt = 0; nt < 4; ++nt) {
    us4 w;
#pragma unroll
    for (int r = 0; r < 4; ++r) {
      const int s = nt * 16 + lg * 4 + r;
      const float v = (s <= trow) ? aT[nt][r] : 0.f;
      rs += v;
      w[r] = f2bf(v);
    }
    *(us4*)&Ks[sidx(trow, nt * 16 + lg * 4)] = w;
  }
  // denominator for row trow: reduce the 4 lg-partials; zv stays lane-local
  float den = rs + zp;
  den += __shfl_xor(den, 16);
  den += __shfl_xor(den, 32);
  const float zv = 1.f / (den + EPSF);

  // ---- out^T-frags: lane holds out[trow][e = nt*16 + lg*4 + r] -> float4 stores ----
  const bf16x8 af0 = *(const bf16x8*)&Ks[sidx(trow, lg * 8)];
  const bf16x8 af1 = *(const bf16x8*)&Ks[sidx(trow, 32 + lg * 8)];
  const size_t obase = ((size_t)(n * L_ + l0 + trow)) * ROWF + h * 64;
#pragma unroll
  for (int nt = 0; nt < 4; ++nt) {
    const int brow = nt * 16 + lane15;   // Vt/St row (e) window
    f32x4 o = {0.f, 0.f, 0.f, 0.f};
    o = MFMA(*(const bf16x8*)&Vt[sidx(brow, lg * 8)], af0, o);
    o = MFMA(*(const bf16x8*)&Vt[sidx(brow, (lg + 4) * 8)], af1, o);
    o = MFMA(*(const bf16x8*)&St[sidx(brow, lg * 8)], qf0, o);
    o = MFMA(*(const bf16x8*)&St[sidx(brow, (lg + 4) * 8)], qf1, o);
    const float4 w = make_float4(o[0] * zv, o[1] * zv, o[2] * zv, o[3] * zv);
    *(float4*)&out[obase + nt * 16 + lg * 4] = w;
  }
}

extern "C" void kernel_launch(void* const* d_in, const int* in_sizes, int n_in,
                              void* d_out, int out_size, void* d_ws, size_t ws_size,
                              hipStream_t stream) {
  const float* queries = (const float*)d_in[0];
  const float* keys    = (const float*)d_in[1];
  const float* values  = (const float*)d_in[2];
  float* out = (float*)d_out;

  // workspace layout:
  //  Tws [NH_*NC_][4096] bf16  (chunk totals -> in-place exclusive prefixes)
  //  Kcs [NH_*NC_][64]   fp32  (chunk colsums -> in-place exclusive prefixes)
  const size_t t_elems = (size_t)NH_ * NC_ * 4096;   // 16.7M bf16 = 33.5 MB
  const size_t k_elems = (size_t)NH_ * NC_ * 64;     // 256K fp32 = 1 MB
  if (ws_size < t_elems * 2 + k_elems * 4) return;
  unsigned short* Tws = (unsigned short*)d_ws;
  float* Kcs = (float*)(Tws + t_elems);

  hipLaunchKernelGGL(k_chunk_tot, dim3(NH_ * NC_), dim3(256), 0, stream, keys, values, Tws, Kcs);
  hipLaunchKernelGGL(k_scan, dim3(512 + 8), dim3(256), 0, stream, Tws, Kcs);
  hipLaunchKernelGGL(k_output, dim3(NH_ * NC_), dim3(256), 0, stream,
                     queries, keys, values, Tws, Kcs, out);
}